// Round 2
// baseline (261.854 us; speedup 1.0000x reference)
//
#include <hip/hip_runtime.h>
#include <math.h>

#define D 4096
#define RPB 4   // rows (= waves) per block

typedef float f4 __attribute__((ext_vector_type(4)));

// Wave-local LDS fence: each wave owns a private LDS slice, so we only need
// this wave's ds ops drained + a compiler reordering barrier — no s_barrier.
__device__ __forceinline__ void wave_lds_fence() {
    __asm__ volatile("s_waitcnt lgkmcnt(0)" ::: "memory");
}

// In-register FWHT over the 6 bits of the register index (64 values/thread).
__device__ __forceinline__ void fwht64(float* v) {
#pragma unroll
    for (int h = 1; h < 64; h <<= 1) {
#pragma unroll
        for (int i = 0; i < 64; i += 2 * h) {
#pragma unroll
            for (int j = i; j < i + h; ++j) {
                const float a = v[j];
                const float b = v[j + h];
                v[j]     = a + b;
                v[j + h] = a - b;
            }
        }
    }
}

// Precompute g = g_mu + softplus(g_rho)*eps, pre-permuted into layout-B order:
// gq[l*64 + k] = g[e(k,l)], e = (l&3) | (k<<2) | ((l>>2)<<8)
__global__ void whvi_prep(const float* __restrict__ g_mu,
                          const float* __restrict__ g_rho,
                          const float* __restrict__ eps,
                          float* __restrict__ gq) {
    const int i = blockIdx.x * 256 + threadIdx.x;  // i = l*64 + k
    const int l = i >> 6, k = i & 63;
    const int e = (l & 3) | (k << 2) | ((l >> 2) << 8);
    const float r  = g_rho[e];
    const float sp = (r > 20.f) ? r : log1pf(expf(r));   // stable softplus
    gq[i] = g_mu[e] + sp * eps[e];
}

// 4 waves/block, one row per wave, private 16 KiB LDS slice per wave.
// Layout A: lane l, reg r holds e = (r&3) | (l<<2) | ((r>>2)<<8)
//           -> register bits {0,1,8,9,10,11}, coalesced b128 global access.
// Layout B: lane l, reg k holds e = (l&3) | (k<<2) | ((l>>2)<<8)
//           -> register bits {2..7}.
// regFWHT(A) -> LDS transpose -> regFWHT(B) covers all 12 bits.
// XOR swizzle sigma(e)=e^((e>>6)&0x1C) keeps b128 writes minimal-phase and
// b32 reads at <=2-way bank aliasing (free per m136).
__global__ void __launch_bounds__(256) whvi_main(
    const float* __restrict__ x,  const float* __restrict__ s1,
    const float* __restrict__ s2, const float* __restrict__ gq,
    const float* __restrict__ g_mu, const float* __restrict__ g_rho,
    const float* __restrict__ eps, float* __restrict__ out) {
    __shared__ alignas(16) float lds_all[RPB][D];   // 64 KiB -> 2 blocks/CU
    const int l = threadIdx.x & 63;
    const int w = threadIdx.x >> 6;
    float* lds = lds_all[w];
    const long long row = (long long)blockIdx.x * RPB + w;
    const float* xr = x + row * (long long)D;
    float v[64];

    // ---- load x*s2, layout A (coalesced dwordx4) ----
#pragma unroll
    for (int q = 0; q < 16; ++q) {
        const int base = (l << 2) + (q << 8);
        const f4 xv = *reinterpret_cast<const f4*>(xr + base);
        const f4 sv = *reinterpret_cast<const f4*>(s2 + base);
        v[4 * q + 0] = xv.x * sv.x;
        v[4 * q + 1] = xv.y * sv.y;
        v[4 * q + 2] = xv.z * sv.z;
        v[4 * q + 3] = xv.w * sv.w;
    }

    fwht64(v);                       // FWHT-1a: e-bits {0,1,8,9,10,11}

    // ---- transpose 1: write layout A (b128), read layout B (b32) ----
#pragma unroll
    for (int q = 0; q < 16; ++q) {
        const int addr = ((l ^ (q & 7)) << 2) + (q << 8);   // swizzled
        f4 t;
        t.x = v[4 * q + 0]; t.y = v[4 * q + 1];
        t.z = v[4 * q + 2]; t.w = v[4 * q + 3];
        *reinterpret_cast<f4*>(&lds[addr]) = t;
    }
    wave_lds_fence();
    {
        const int xb = (l & 3) | ((l >> 2) << 8);
        const int mk = (l >> 2) & 7;                        // swizzle mask
#pragma unroll
        for (int k = 0; k < 64; ++k)
            v[k] = lds[xb + ((k ^ mk) << 2)];
    }

    fwht64(v);                       // FWHT-1b: e-bits {2..7}  (FWHT #1 done)

    // ---- multiply by g (pre-permuted, L1-resident) ----
    if (gq) {
#pragma unroll
        for (int m = 0; m < 16; ++m) {
            const f4 gv = *reinterpret_cast<const f4*>(gq + l * 64 + 4 * m);
            v[4 * m + 0] *= gv.x;
            v[4 * m + 1] *= gv.y;
            v[4 * m + 2] *= gv.z;
            v[4 * m + 3] *= gv.w;
        }
    } else {  // fallback if d_ws too small: compute softplus inline
#pragma unroll
        for (int k = 0; k < 64; ++k) {
            const int e = (l & 3) | (k << 2) | ((l >> 2) << 8);
            const float r  = g_rho[e];
            const float sp = (r > 20.f) ? r : log1pf(expf(r));
            v[k] *= g_mu[e] + sp * eps[e];
        }
    }

    fwht64(v);                       // FWHT-2a: e-bits {2..7}

    // ---- transpose 2: write layout B (b32), read layout A (b128) ----
    wave_lds_fence();                // order vs transpose-1 reads (WAR)
    {
        const int xb = (l & 3) | ((l >> 2) << 8);
        const int mk = (l >> 2) & 7;
#pragma unroll
        for (int k = 0; k < 64; ++k)
            lds[xb + ((k ^ mk) << 2)] = v[k];
    }
    wave_lds_fence();
#pragma unroll
    for (int q = 0; q < 16; ++q) {
        const int addr = ((l ^ (q & 7)) << 2) + (q << 8);
        const f4 t = *reinterpret_cast<const f4*>(&lds[addr]);
        v[4 * q + 0] = t.x;
        v[4 * q + 1] = t.y;
        v[4 * q + 2] = t.z;
        v[4 * q + 3] = t.w;
    }

    fwht64(v);                       // FWHT-2b: e-bits {0,1,8,9,10,11}

    // ---- multiply by s1, nontemporal store (don't evict x from L3) ----
    float* outr = out + row * (long long)D;
#pragma unroll
    for (int q = 0; q < 16; ++q) {
        const int base = (l << 2) + (q << 8);
        const f4 sv = *reinterpret_cast<const f4*>(s1 + base);
        f4 o;
        o.x = v[4 * q + 0] * sv.x;
        o.y = v[4 * q + 1] * sv.y;
        o.z = v[4 * q + 2] * sv.z;
        o.w = v[4 * q + 3] * sv.w;
        __builtin_nontemporal_store(o, reinterpret_cast<f4*>(outr + base));
    }
}

extern "C" void kernel_launch(void* const* d_in, const int* in_sizes, int n_in,
                              void* d_out, int out_size, void* d_ws, size_t ws_size,
                              hipStream_t stream) {
    const float* x     = (const float*)d_in[0];
    const float* s1    = (const float*)d_in[1];
    const float* s2    = (const float*)d_in[2];
    const float* g_mu  = (const float*)d_in[3];
    const float* g_rho = (const float*)d_in[4];
    const float* eps   = (const float*)d_in[5];
    float* out = (float*)d_out;
    const int rows = in_sizes[0] / D;

    float* gq = nullptr;
    if (ws_size >= (size_t)D * sizeof(float)) {
        gq = (float*)d_ws;
        whvi_prep<<<D / 256, 256, 0, stream>>>(g_mu, g_rho, eps, gq);
    }
    whvi_main<<<rows / RPB, 256, 0, stream>>>(x, s1, s2, gq, g_mu, g_rho, eps, out);
}

// Round 3
// 254.867 us; speedup vs baseline: 1.0274x; 1.0274x over previous
//
#include <hip/hip_runtime.h>
#include <math.h>

#define D 4096
#define RPB 2
#define STRIDE 68   // 64 + 4 pad: b128 phases tile all 32 banks; 272 B row = 16B-aligned

typedef float f4 __attribute__((ext_vector_type(4)));

// Wave-private LDS slice: only this wave's ds ops need draining; no s_barrier.
__device__ __forceinline__ void wave_lds_fence() {
    __asm__ volatile("s_waitcnt lgkmcnt(0)" ::: "memory");
}

// In-register FWHT over the 6 bits of the register index (64 values/thread).
__device__ __forceinline__ void fwht64(float* v) {
#pragma unroll
    for (int h = 1; h < 64; h <<= 1) {
#pragma unroll
        for (int i = 0; i < 64; i += 2 * h) {
#pragma unroll
            for (int j = i; j < i + h; ++j) {
                const float a = v[j];
                const float b = v[j + h];
                v[j]     = a + b;
                v[j + h] = a - b;
            }
        }
    }
}

// g = g_mu + softplus(g_rho)*eps, pre-permuted to B-layout:
// gq[l*64 + k] = g[e], e = (l&3) | (k<<2) | ((l>>2)<<8)
__global__ void whvi_prep(const float* __restrict__ g_mu,
                          const float* __restrict__ g_rho,
                          const float* __restrict__ eps,
                          float* __restrict__ gq) {
    const int i = blockIdx.x * 256 + threadIdx.x;  // i = l*64 + k
    const int l = i >> 6, k = i & 63;
    const int e = (l & 3) | (k << 2) | ((l >> 2) << 8);
    const float r  = g_rho[e];
    const float sp = (r > 20.f) ? r : log1pf(expf(r));   // stable softplus
    gq[i] = g_mu[e] + sp * eps[e];
}

// One wave per row, 2 rows/block. 64 elems/lane.
// Layout A: lane l, reg r holds e = (r&3) | (l<<2) | ((r>>2)<<8)
//           -> reg bits {0,1,8,9,10,11}; coalesced b128 global access.
// Layout B: lane l, reg k holds e = (l&3) | (k<<2) | ((l>>2)<<8)
//           -> reg bits {2..7}.
// Note uB(e) = e[1:0]|(e[11:8]<<2) = r exactly, so the LDS transpose is:
//   write lds[r*STRIDE + l]  (scatter rows, 2-way banks = free)
//   read  lds[l*STRIDE + 4t] as float4 (stride-68 rows tile 32 banks)
// Both sides are base + compile-time immediate: zero per-element VALU.
__global__ void __launch_bounds__(128, 4) whvi_main(
    const float* __restrict__ x,  const float* __restrict__ s1,
    const float* __restrict__ s2, const float* __restrict__ gq,
    const float* __restrict__ g_mu, const float* __restrict__ g_rho,
    const float* __restrict__ eps, float* __restrict__ out) {
    __shared__ alignas(16) float lds_all[RPB][64 * STRIDE];  // 34816 B/block
    const int l = threadIdx.x & 63;
    const int w = threadIdx.x >> 6;
    float* lds = lds_all[w];
    const long long row = (long long)blockIdx.x * RPB + w;
    const float* xr = x + row * (long long)D;
    float v[64];

    // ---- burst ALL x loads straight into v (16 KB in flight per wave) ----
#pragma unroll
    for (int q = 0; q < 16; ++q)
        *reinterpret_cast<f4*>(&v[4 * q]) =
            *reinterpret_cast<const f4*>(xr + (l << 2) + (q << 8));

    // ---- then multiply by s2 (L2-resident) ----
#pragma unroll
    for (int q = 0; q < 16; ++q) {
        const f4 s = *reinterpret_cast<const f4*>(s2 + (l << 2) + (q << 8));
        v[4 * q + 0] *= s.x;
        v[4 * q + 1] *= s.y;
        v[4 * q + 2] *= s.z;
        v[4 * q + 3] *= s.w;
    }

    fwht64(v);                       // FWHT-1a: e-bits {0,1,8,9,10,11}

    // ---- transpose 1: scatter-write rows, gather-read own row as b128 ----
#pragma unroll
    for (int r = 0; r < 64; ++r)
        lds[r * STRIDE + l] = v[r];
    wave_lds_fence();
#pragma unroll
    for (int t = 0; t < 16; ++t)
        *reinterpret_cast<f4*>(&v[4 * t]) =
            *reinterpret_cast<const f4*>(&lds[l * STRIDE + 4 * t]);

    fwht64(v);                       // FWHT-1b: e-bits {2..7}  (FWHT #1 done)

    // ---- multiply by g (pre-permuted, L1/L2-resident) ----
    if (gq) {
#pragma unroll
        for (int t = 0; t < 16; ++t) {
            const f4 g = *reinterpret_cast<const f4*>(gq + (l << 6) + (t << 2));
            v[4 * t + 0] *= g.x;
            v[4 * t + 1] *= g.y;
            v[4 * t + 2] *= g.z;
            v[4 * t + 3] *= g.w;
        }
    } else {  // fallback if d_ws too small
#pragma unroll
        for (int k = 0; k < 64; ++k) {
            const int e = (l & 3) | (k << 2) | ((l >> 2) << 8);
            const float r  = g_rho[e];
            const float sp = (r > 20.f) ? r : log1pf(expf(r));
            v[k] *= g_mu[e] + sp * eps[e];
        }
    }

    fwht64(v);                       // FWHT-2a: e-bits {2..7}

    // ---- transpose 2: b128 write own row, scatter-read columns ----
    wave_lds_fence();                // WAR vs transpose-1 reads
#pragma unroll
    for (int t = 0; t < 16; ++t)
        *reinterpret_cast<f4*>(&lds[l * STRIDE + 4 * t]) =
            *reinterpret_cast<const f4*>(&v[4 * t]);
    wave_lds_fence();
#pragma unroll
    for (int r = 0; r < 64; ++r)
        v[r] = lds[r * STRIDE + l];

    fwht64(v);                       // FWHT-2b: e-bits {0,1,8,9,10,11}

    // ---- multiply by s1, coalesced b128 store ----
    float* outr = out + row * (long long)D;
#pragma unroll
    for (int q = 0; q < 16; ++q) {
        const f4 s = *reinterpret_cast<const f4*>(s1 + (l << 2) + (q << 8));
        f4 o;
        o.x = v[4 * q + 0] * s.x;
        o.y = v[4 * q + 1] * s.y;
        o.z = v[4 * q + 2] * s.z;
        o.w = v[4 * q + 3] * s.w;
        *reinterpret_cast<f4*>(outr + (l << 2) + (q << 8)) = o;
    }
}

extern "C" void kernel_launch(void* const* d_in, const int* in_sizes, int n_in,
                              void* d_out, int out_size, void* d_ws, size_t ws_size,
                              hipStream_t stream) {
    const float* x     = (const float*)d_in[0];
    const float* s1    = (const float*)d_in[1];
    const float* s2    = (const float*)d_in[2];
    const float* g_mu  = (const float*)d_in[3];
    const float* g_rho = (const float*)d_in[4];
    const float* eps   = (const float*)d_in[5];
    float* out = (float*)d_out;
    const int rows = in_sizes[0] / D;

    float* gq = nullptr;
    if (ws_size >= (size_t)D * sizeof(float)) {
        gq = (float*)d_ws;
        whvi_prep<<<D / 256, 256, 0, stream>>>(g_mu, g_rho, eps, gq);
    }
    whvi_main<<<rows / RPB, 128, 0, stream>>>(x, s1, s2, gq, g_mu, g_rho, eps, out);
}